// Round 9
// baseline (401.492 us; speedup 1.0000x reference)
//
#include <hip/hip_runtime.h>
#include <hip/hip_bf16.h>
#include <stdint.h>

#define N_CLOTH     16384
#define N_OBS_VERTS 8192
#define N_OBS_FACES 16384

#define GRID_N  16
#define NCELL   (GRID_N * GRID_N * GRID_N)     // 4096
#define GLO     (-2.6f)
#define GH      (5.2f / 16.0f)                 // 0.325
#define GINVH   (1.0f / GH)
#define MARGIN  1e-3f                          // d^2-space safety margin (>> fp rounding)

__device__ __forceinline__ unsigned enc_f32(float x) {
    unsigned u = __float_as_uint(x);
    return (u & 0x80000000u) ? ~u : (u | 0x80000000u);   // monotone map
}
__device__ __forceinline__ float dec_f32(unsigned u) {
    u = (u & 0x80000000u) ? (u & 0x7FFFFFFFu) : ~u;
    return __uint_as_float(u);
}

// ---------------------------------------------------------------------------
// K1: per-face: prev center + 0.5||c||^2 -> faceA; bin into grid (count +
// exact per-cell bbox via encoded atomics); record cell id.
// ---------------------------------------------------------------------------
__global__ __launch_bounds__(256) void k_facesbin(
    const float* __restrict__ obs_prev, const int* __restrict__ faces,
    float4* __restrict__ faceA, int* __restrict__ cellOf,
    int* __restrict__ cnt,
    unsigned int* __restrict__ bbMinEnc, unsigned int* __restrict__ bbMaxEnc)
{
    int f = blockIdx.x * 256 + threadIdx.x;
    if (f >= N_OBS_FACES) return;
    int i0 = faces[3 * f + 0];
    int i1 = faces[3 * f + 1];
    int i2 = faces[3 * f + 2];
    float ax = obs_prev[3 * i0 + 0], ay = obs_prev[3 * i0 + 1], az = obs_prev[3 * i0 + 2];
    float bx = obs_prev[3 * i1 + 0], by = obs_prev[3 * i1 + 1], bz = obs_prev[3 * i1 + 2];
    float cx = obs_prev[3 * i2 + 0], cy = obs_prev[3 * i2 + 1], cz = obs_prev[3 * i2 + 2];
    float pcx = (ax + bx + cx) * (1.0f / 3.0f);
    float pcy = (ay + by + cy) * (1.0f / 3.0f);
    float pcz = (az + bz + cz) * (1.0f / 3.0f);
    float b2h = 0.5f * (pcx * pcx + pcy * pcy + pcz * pcz);
    faceA[f] = make_float4(pcx, pcy, pcz, b2h);

    int gx = min(max((int)floorf((pcx - GLO) * GINVH), 0), GRID_N - 1);
    int gy = min(max((int)floorf((pcy - GLO) * GINVH), 0), GRID_N - 1);
    int gz = min(max((int)floorf((pcz - GLO) * GINVH), 0), GRID_N - 1);
    int cell = (gz * GRID_N + gy) * GRID_N + gx;
    cellOf[f] = cell;
    atomicAdd(&cnt[cell], 1);
    atomicMin(&bbMinEnc[3 * cell + 0], enc_f32(pcx));
    atomicMin(&bbMinEnc[3 * cell + 1], enc_f32(pcy));
    atomicMin(&bbMinEnc[3 * cell + 2], enc_f32(pcz));
    atomicMax(&bbMaxEnc[3 * cell + 0], enc_f32(pcx));
    atomicMax(&bbMaxEnc[3 * cell + 1], enc_f32(pcy));
    atomicMax(&bbMaxEnc[3 * cell + 2], enc_f32(pcz));
}

// ---------------------------------------------------------------------------
// K2: single-block exclusive prefix sum over 4096 counts -> start/cursor;
// decode per-cell bboxes to float4.
// ---------------------------------------------------------------------------
__global__ __launch_bounds__(1024) void k_scan(
    const int* __restrict__ cnt, int* __restrict__ start, int* __restrict__ cursor,
    const unsigned int* __restrict__ bbMinEnc, const unsigned int* __restrict__ bbMaxEnc,
    float4* __restrict__ bbLo, float4* __restrict__ bbHi)
{
    __shared__ int part[1024];
    int t = threadIdx.x;
    int local[4];
    int s0 = 0;
#pragma unroll
    for (int i = 0; i < 4; ++i) { local[i] = s0; s0 += cnt[t * 4 + i]; }
    part[t] = s0;
    __syncthreads();
    for (int off = 1; off < 1024; off <<= 1) {
        int v = (t >= off) ? part[t - off] : 0;
        __syncthreads();
        part[t] += v;
        __syncthreads();
    }
    int base = (t > 0) ? part[t - 1] : 0;
#pragma unroll
    for (int i = 0; i < 4; ++i) {
        int c = t * 4 + i;
        int st = base + local[i];
        start[c] = st;
        cursor[c] = st;
        bbLo[c] = make_float4(dec_f32(bbMinEnc[3 * c + 0]), dec_f32(bbMinEnc[3 * c + 1]),
                              dec_f32(bbMinEnc[3 * c + 2]), 0.0f);
        bbHi[c] = make_float4(dec_f32(bbMaxEnc[3 * c + 0]), dec_f32(bbMaxEnc[3 * c + 1]),
                              dec_f32(bbMaxEnc[3 * c + 2]), 0.0f);
    }
}

// ---------------------------------------------------------------------------
// K3: scatter faces into cell-sorted order (faceAS + origIdx).
// Order within a cell is nondeterministic (atomic), but the final key-min is
// a min over a set -> result deterministic & exact.
// ---------------------------------------------------------------------------
__global__ __launch_bounds__(256) void k_scatter(
    const float4* __restrict__ faceA, const int* __restrict__ cellOf,
    int* __restrict__ cursor, float4* __restrict__ faceAS, int* __restrict__ origIdx)
{
    int f = blockIdx.x * 256 + threadIdx.x;
    if (f >= N_OBS_FACES) return;
    int cell = cellOf[f];
    int p = atomicAdd(&cursor[cell], 1);
    faceAS[p] = faceA[f];
    origIdx[p] = f;
}

// ---------------------------------------------------------------------------
// K4: exact grid 1-NN. 8 lanes per vertex; shell walk with bbox pruning.
// s = 0.5||b||^2 - a.b via the bit-identical fmaf chain; key=(mono(s)<<32)|idx
// -> min over evaluated set == global argmin with lowest-index ties, because
// pruning only removes faces with provable s > best + (margin-protected).
// ---------------------------------------------------------------------------
__global__ __launch_bounds__(256) void k_nn_grid(
    const float* __restrict__ cloth_prev,
    const float4* __restrict__ faceAS, const int* __restrict__ origIdx,
    const int* __restrict__ cnt, const int* __restrict__ start,
    const float4* __restrict__ bbLo, const float4* __restrict__ bbHi,
    unsigned long long* __restrict__ keys)
{
    const int t = threadIdx.x;
    const int r = t & 7;                         // role 0..7
    const int n = blockIdx.x * 32 + (t >> 3);    // vertex id

    const float vx = cloth_prev[3 * n + 0];
    const float vy = cloth_prev[3 * n + 1];
    const float vz = cloth_prev[3 * n + 2];
    const float vv = vx * vx + vy * vy + vz * vz;

    const int hx = min(max((int)floorf((vx - GLO) * GINVH), 0), GRID_N - 1);
    const int hy = min(max((int)floorf((vy - GLO) * GINVH), 0), GRID_N - 1);
    const int hz = min(max((int)floorf((vz - GLO) * GINVH), 0), GRID_N - 1);

    unsigned long long key = 0xFFFFFFFFFFFFFFFFull;
    // d2best decode: unset key -> NaN -> all prune/stop comparisons false (safe)
    float d2best = __uint_as_float(0x7FC00000u);

    auto evalCell = [&](int cx, int cy, int cz) {
        int cell = (cz * GRID_N + cy) * GRID_N + cx;
        int c0 = cnt[cell];
        if (c0 == 0) return;
        float4 lo = bbLo[cell];
        float4 hi = bbHi[cell];
        float dxx = fmaxf(fmaxf(lo.x - vx, vx - hi.x), 0.0f);
        float dyy = fmaxf(fmaxf(lo.y - vy, vy - hi.y), 0.0f);
        float dzz = fmaxf(fmaxf(lo.z - vz, vz - hi.z), 0.0f);
        float lbsq = dxx * dxx + dyy * dyy + dzz * dzz;
        if (lbsq > d2best + MARGIN) return;      // conservative prune
        int st = start[cell];
        for (int i = st + r; i < st + c0; i += 8) {
            float4 b = faceAS[i];
            float s = fmaf(-vx, b.x, b.w);
            s = fmaf(-vy, b.y, s);
            s = fmaf(-vz, b.z, s);
            unsigned u = __float_as_uint(s);
            u = (u & 0x80000000u) ? ~u : (u | 0x80000000u);
            unsigned long long k = ((unsigned long long)u << 32) | (unsigned)origIdx[i];
            key = (k < key) ? k : key;
        }
        d2best = 2.0f * dec_f32((unsigned)(key >> 32)) + vv;
    };

    for (int S = 0; S < GRID_N; ++S) {
        // stop: farther shells have min distance >= (S-1)*h (group-uniform)
        float stopd = (float)(S - 1) * GH;
        if (stopd * stopd > d2best + MARGIN) break;

        for (int dz = -S; dz <= S; ++dz) {
            int cz = hz + dz;
            if ((unsigned)cz >= GRID_N) continue;
            bool zedge = (dz == -S) || (dz == S);
            for (int dy = -S; dy <= S; ++dy) {
                int cy = hy + dy;
                if ((unsigned)cy >= GRID_N) continue;
                bool yedge = (dy == -S) || (dy == S);
                if (zedge || yedge) {
                    for (int dx = -S; dx <= S; ++dx) {
                        int cx = hx + dx;
                        if ((unsigned)cx >= GRID_N) continue;
                        evalCell(cx, cy, cz);
                    }
                } else {
                    int cx = hx - S;
                    if (cx >= 0) evalCell(cx, cy, cz);
                    cx = hx + S;
                    if (cx < GRID_N) evalCell(cx, cy, cz);
                }
            }
        }
        // combine roles (group-uniform d2best for stop + stronger pruning)
        unsigned long long o = __shfl_xor(key, 1);
        key = (o < key) ? o : key;
        o = __shfl_xor(key, 2);
        key = (o < key) ? o : key;
        o = __shfl_xor(key, 4);
        key = (o < key) ? o : key;
        d2best = 2.0f * dec_f32((unsigned)(key >> 32)) + vv;
    }

    if (r == 0) keys[n] = key;
}

// ---------------------------------------------------------------------------
// K5: gather chosen face, current center + unit normal on the fly, cubic
// penalty, block-sum -> lossPartial[64]
// ---------------------------------------------------------------------------
__global__ __launch_bounds__(256) void k_loss(
    const float* __restrict__ cloth_pred,
    const float* __restrict__ obs_pos,
    const int* __restrict__ faces,
    const unsigned long long* __restrict__ keys,
    float* __restrict__ lossPartial)
{
    const int t = threadIdx.x;
    const int n = blockIdx.x * blockDim.x + t;

    int idx = (int)(unsigned int)(keys[n] & 0xFFFFFFFFull);

    int i0 = faces[3 * idx + 0];
    int i1 = faces[3 * idx + 1];
    int i2 = faces[3 * idx + 2];
    float ux = obs_pos[3 * i0 + 0], uy = obs_pos[3 * i0 + 1], uz = obs_pos[3 * i0 + 2];
    float wx1 = obs_pos[3 * i1 + 0], wy1 = obs_pos[3 * i1 + 1], wz1 = obs_pos[3 * i1 + 2];
    float wx2 = obs_pos[3 * i2 + 0], wy2 = obs_pos[3 * i2 + 1], wz2 = obs_pos[3 * i2 + 2];

    float fpx = (ux + wx1 + wx2) * (1.0f / 3.0f);
    float fpy = (uy + wy1 + wy2) * (1.0f / 3.0f);
    float fpz = (uz + wz1 + wz2) * (1.0f / 3.0f);

    float e1x = wx1 - ux, e1y = wy1 - uy, e1z = wz1 - uz;
    float e2x = wx2 - ux, e2y = wy2 - uy, e2z = wz2 - uz;
    float nx = e1y * e2z - e1z * e2y;
    float ny = e1z * e2x - e1x * e2z;
    float nz = e1x * e2y - e1y * e2x;
    float nrm = sqrtf(nx * nx + ny * ny + nz * nz);
    float inv = 1.0f / fmaxf(nrm, 1e-12f);

    float px = cloth_pred[3 * n + 0];
    float py = cloth_pred[3 * n + 1];
    float pz = cloth_pred[3 * n + 2];
    float d = (px - fpx) * nx * inv + (py - fpy) * ny * inv + (pz - fpz) * nz * inv;
    float tt = fmaxf(1e-3f - d, 0.0f);
    float val = tt * tt * tt;

    __shared__ float red[256];
    red[t] = val;
    __syncthreads();
    for (int s = 128; s > 0; s >>= 1) {
        if (t < s) red[t] += red[t + s];
        __syncthreads();
    }
    if (t == 0) lossPartial[blockIdx.x] = red[0];
}

// ---------------------------------------------------------------------------
// K6: final 64-partial sum * weight(iteration) -> d_out[0] (pure overwrite)
// ---------------------------------------------------------------------------
__global__ __launch_bounds__(64) void k_final(
    const float* __restrict__ lossPartial,
    const int* __restrict__ iteration,
    float* __restrict__ out)
{
    int t = threadIdx.x;
    float v = lossPartial[t];
#pragma unroll
    for (int o = 32; o > 0; o >>= 1) v += __shfl_down(v, o);
    if (t == 0) {
        int it = iteration[0];
        float itf = fmaxf((float)(it - 50000), 0.0f);
        float prog = fminf(itf * (1.0f / 100000.0f), 1.0f);
        float w = 1.0f + (5000.0f - 1.0f) * prog;
        out[0] = v * w;
    }
}

extern "C" void kernel_launch(void* const* d_in, const int* in_sizes, int n_in,
                              void* d_out, int out_size, void* d_ws, size_t ws_size,
                              hipStream_t stream) {
    const float* obs_pos    = (const float*)d_in[0];
    const float* obs_prev   = (const float*)d_in[1];
    const int*   faces      = (const int*)d_in[2];
    const float* cloth_prev = (const float*)d_in[3];
    const float* cloth_pred = (const float*)d_in[4];
    const int*   iteration  = (const int*)d_in[5];
    float* out = (float*)d_out;

    char* ws = (char*)d_ws;
    float4*       faceA     = (float4*)(ws + 0);            // 256 KB
    float4*       faceAS    = (float4*)(ws + 262144);       // 256 KB
    int*          origIdx   = (int*)(ws + 524288);          // 64 KB
    int*          cellOf    = (int*)(ws + 589824 - 65536);  // reuse? no -- see below
    // layout (fresh, no overlap):
    //   0        faceA      262144
    //   262144   faceAS     262144
    //   524288   origIdx     65536
    //   589824   cellOf      65536
    //   655360   cnt         16384   \ zero-memset region (cnt + bbMaxEnc)
    //   671744   bbMaxEnc    49152   /
    //   720896   bbMinEnc    49152   <- 0xFF memset
    //   770048   start       16384
    //   786432   cursor      16384
    //   802816   bbLo        65536
    //   868352   bbHi        65536
    //   933888   keys       131072
    //   1064960  lossPartial   256
    cellOf                  = (int*)(ws + 589824);
    int*          cnt       = (int*)(ws + 655360);
    unsigned int* bbMaxEnc  = (unsigned int*)(ws + 671744);
    unsigned int* bbMinEnc  = (unsigned int*)(ws + 720896);
    int*          startArr  = (int*)(ws + 770048);
    int*          cursor    = (int*)(ws + 786432);
    float4*       bbLo      = (float4*)(ws + 802816);
    float4*       bbHi      = (float4*)(ws + 868352);
    unsigned long long* keys = (unsigned long long*)(ws + 933888);
    float*        lossPartial = (float*)(ws + 1064960);

    hipMemsetAsync(ws + 655360, 0x00, 16384 + 49152, stream);   // cnt + bbMaxEnc
    hipMemsetAsync(ws + 720896, 0xFF, 49152, stream);           // bbMinEnc

    k_facesbin<<<N_OBS_FACES / 256, 256, 0, stream>>>(
        obs_prev, faces, faceA, cellOf, cnt, bbMinEnc, bbMaxEnc);
    k_scan<<<1, 1024, 0, stream>>>(cnt, startArr, cursor, bbMinEnc, bbMaxEnc, bbLo, bbHi);
    k_scatter<<<N_OBS_FACES / 256, 256, 0, stream>>>(faceA, cellOf, cursor, faceAS, origIdx);
    k_nn_grid<<<N_CLOTH * 8 / 256, 256, 0, stream>>>(
        cloth_prev, faceAS, origIdx, cnt, startArr, bbLo, bbHi, keys);
    k_loss<<<N_CLOTH / 256, 256, 0, stream>>>(cloth_pred, obs_pos, faces, keys, lossPartial);
    k_final<<<1, 64, 0, stream>>>(lossPartial, iteration, out);
}

// Round 10
// 129.227 us; speedup vs baseline: 3.1069x; 3.1069x over previous
//
#include <hip/hip_runtime.h>
#include <hip/hip_bf16.h>
#include <stdint.h>

#define N_CLOTH     16384
#define N_OBS_VERTS 8192
#define N_OBS_FACES 16384

#define GRID_N  16
#define NCELL   4096
#define GLO     (-2.6f)
#define GH      (5.2f / 16.0f)
#define GINVH   (1.0f / GH)
#define MARGIN  1e-3f      // d^2-space safety margin (>> fp rounding error)

#define NCH  256           // face chunks (all full: 16384/64)
#define CHF  64            // faces per chunk
#define K5_VB 32           // verts per k_nn_cull block

__device__ __forceinline__ unsigned enc_f32(float x) {
    unsigned u = __float_as_uint(x);
    return (u & 0x80000000u) ? ~u : (u | 0x80000000u);
}
__device__ __forceinline__ float dec_f32(unsigned u) {
    u = (u & 0x80000000u) ? (u & 0x7FFFFFFFu) : ~u;
    return __uint_as_float(u);
}
__device__ __forceinline__ int expand4(int v) {
    return (v & 1) | ((v & 2) << 2) | ((v & 4) << 4) | ((v & 8) << 6);
}
__device__ __forceinline__ int mcell(float x, float y, float z) {
    int gx = min(max((int)floorf((x - GLO) * GINVH), 0), GRID_N - 1);
    int gy = min(max((int)floorf((y - GLO) * GINVH), 0), GRID_N - 1);
    int gz = min(max((int)floorf((z - GLO) * GINVH), 0), GRID_N - 1);
    return expand4(gx) | (expand4(gy) << 1) | (expand4(gz) << 2);
}

// ---------------------------------------------------------------------------
// K1: faceA (prev center + 0.5||c||^2) + Morton cell ids + histogram both sets
// ---------------------------------------------------------------------------
__global__ __launch_bounds__(256) void k_bin(
    const float* __restrict__ obs_prev, const int* __restrict__ faces,
    const float* __restrict__ cloth_prev,
    float4* __restrict__ faceA, int* __restrict__ cellF, int* __restrict__ cellV,
    int* __restrict__ faceCnt, int* __restrict__ vertCnt)
{
    int i = blockIdx.x * 256 + threadIdx.x;
    int i0 = faces[3 * i + 0];
    int i1 = faces[3 * i + 1];
    int i2 = faces[3 * i + 2];
    float ax = obs_prev[3 * i0 + 0], ay = obs_prev[3 * i0 + 1], az = obs_prev[3 * i0 + 2];
    float bx = obs_prev[3 * i1 + 0], by = obs_prev[3 * i1 + 1], bz = obs_prev[3 * i1 + 2];
    float cx = obs_prev[3 * i2 + 0], cy = obs_prev[3 * i2 + 1], cz = obs_prev[3 * i2 + 2];
    float pcx = (ax + bx + cx) * (1.0f / 3.0f);
    float pcy = (ay + by + cy) * (1.0f / 3.0f);
    float pcz = (az + bz + cz) * (1.0f / 3.0f);
    float b2h = 0.5f * (pcx * pcx + pcy * pcy + pcz * pcz);
    faceA[i] = make_float4(pcx, pcy, pcz, b2h);
    int cf = mcell(pcx, pcy, pcz);
    cellF[i] = cf;
    atomicAdd(&faceCnt[cf], 1);

    float vx = cloth_prev[3 * i + 0];
    float vy = cloth_prev[3 * i + 1];
    float vz = cloth_prev[3 * i + 2];
    int cv = mcell(vx, vy, vz);
    cellV[i] = cv;
    atomicAdd(&vertCnt[cv], 1);
}

// ---------------------------------------------------------------------------
// K2: two exclusive scans (4096 each): faceCnt -> faceStart/cursorF,
// vertCnt -> cursorV
// ---------------------------------------------------------------------------
__global__ __launch_bounds__(1024) void k_scan2(
    const int* __restrict__ faceCnt, const int* __restrict__ vertCnt,
    int* __restrict__ faceStart, int* __restrict__ cursorF, int* __restrict__ cursorV)
{
    __shared__ int part[1024];
    int t = threadIdx.x;
    int l[4];
    int s0 = 0;
#pragma unroll
    for (int i = 0; i < 4; ++i) { l[i] = s0; s0 += faceCnt[t * 4 + i]; }
    part[t] = s0;
    __syncthreads();
    for (int off = 1; off < 1024; off <<= 1) {
        int v = (t >= off) ? part[t - off] : 0;
        __syncthreads();
        part[t] += v;
        __syncthreads();
    }
    int base = (t > 0) ? part[t - 1] : 0;
#pragma unroll
    for (int i = 0; i < 4; ++i) {
        faceStart[t * 4 + i] = base + l[i];
        cursorF[t * 4 + i] = base + l[i];
    }
    __syncthreads();
    s0 = 0;
#pragma unroll
    for (int i = 0; i < 4; ++i) { l[i] = s0; s0 += vertCnt[t * 4 + i]; }
    part[t] = s0;
    __syncthreads();
    for (int off = 1; off < 1024; off <<= 1) {
        int v = (t >= off) ? part[t - off] : 0;
        __syncthreads();
        part[t] += v;
        __syncthreads();
    }
    base = (t > 0) ? part[t - 1] : 0;
#pragma unroll
    for (int i = 0; i < 4; ++i) cursorV[t * 4 + i] = base + l[i];
}

// ---------------------------------------------------------------------------
// K3: scatter faces and verts into cell-sorted order. Order within a cell is
// nondeterministic; final result is a min over a set -> deterministic output.
// ---------------------------------------------------------------------------
__global__ __launch_bounds__(256) void k_scatter(
    const float4* __restrict__ faceA, const int* __restrict__ cellF,
    const float* __restrict__ cloth_prev, const int* __restrict__ cellV,
    int* __restrict__ cursorF, int* __restrict__ cursorV,
    float4* __restrict__ faceAS, int* __restrict__ origIdx, float4* __restrict__ vertS)
{
    int i = blockIdx.x * 256 + threadIdx.x;
    int p = atomicAdd(&cursorF[cellF[i]], 1);
    faceAS[p] = faceA[i];
    origIdx[p] = i;
    int q = atomicAdd(&cursorV[cellV[i]], 1);
    vertS[q] = make_float4(cloth_prev[3 * i + 0], cloth_prev[3 * i + 1],
                           cloth_prev[3 * i + 2], __uint_as_float((unsigned)i));
}

// ---------------------------------------------------------------------------
// K4: exact AABB per 64-face chunk
// ---------------------------------------------------------------------------
__global__ __launch_bounds__(64) void k_chunkbb(
    const float4* __restrict__ faceAS,
    float4* __restrict__ bbLo, float4* __restrict__ bbHi)
{
    int c = blockIdx.x, t = threadIdx.x;
    float4 a = faceAS[c * CHF + t];
    float mnx = a.x, mny = a.y, mnz = a.z, mxx = a.x, mxy = a.y, mxz = a.z;
    for (int d = 1; d < 64; d <<= 1) {
        mnx = fminf(mnx, __shfl_xor(mnx, d));
        mny = fminf(mny, __shfl_xor(mny, d));
        mnz = fminf(mnz, __shfl_xor(mnz, d));
        mxx = fmaxf(mxx, __shfl_xor(mxx, d));
        mxy = fmaxf(mxy, __shfl_xor(mxy, d));
        mxz = fmaxf(mxz, __shfl_xor(mxz, d));
    }
    if (t == 0) {
        bbLo[c] = make_float4(mnx, mny, mnz, 0.0f);
        bbHi[c] = make_float4(mxx, mxy, mxz, 0.0f);
    }
}

// ---------------------------------------------------------------------------
// K5: culled NN. Block = 32 sorted verts x 8 roles (256 thr, 512 blocks).
// pass A: per-vert home chunk -> tight ub. Block AABB + per-chunk lb ->
// ballot-compacted survivor list. Main loop: per-vert lb skip + 8 coalesced
// face evals per thread. key = (mono(s)<<32)|orig -> exact jnp.argmin.
// ---------------------------------------------------------------------------
__global__ __launch_bounds__(256) void k_nn_cull(
    const float4* __restrict__ vertS,
    const float4* __restrict__ faceAS, const int* __restrict__ origIdx,
    const int* __restrict__ faceStart,
    const float4* __restrict__ bbLo, const float4* __restrict__ bbHi,
    unsigned long long* __restrict__ keys)
{
    const int t = threadIdx.x;
    const int role = t & 7;
    const int lv = t >> 3;    // local vert 0..31
    const int wv = t >> 6;    // wave 0..3

    float4 V = vertS[blockIdx.x * K5_VB + lv];
    const float vx = V.x, vy = V.y, vz = V.z;
    const unsigned n_orig = __float_as_uint(V.w);
    const float vv = vx * vx + vy * vy + vz * vz;

    // block AABB
    __shared__ float bbw[4][6];
    {
        float mnx = vx, mny = vy, mnz = vz, mxx = vx, mxy = vy, mxz = vz;
        for (int d = 1; d < 64; d <<= 1) {
            mnx = fminf(mnx, __shfl_xor(mnx, d));
            mny = fminf(mny, __shfl_xor(mny, d));
            mnz = fminf(mnz, __shfl_xor(mnz, d));
            mxx = fmaxf(mxx, __shfl_xor(mxx, d));
            mxy = fmaxf(mxy, __shfl_xor(mxy, d));
            mxz = fmaxf(mxz, __shfl_xor(mxz, d));
        }
        if ((t & 63) == 0) {
            bbw[wv][0] = mnx; bbw[wv][1] = mny; bbw[wv][2] = mnz;
            bbw[wv][3] = mxx; bbw[wv][4] = mxy; bbw[wv][5] = mxz;
        }
    }
    __syncthreads();
    const float bmnx = fminf(fminf(bbw[0][0], bbw[1][0]), fminf(bbw[2][0], bbw[3][0]));
    const float bmny = fminf(fminf(bbw[0][1], bbw[1][1]), fminf(bbw[2][1], bbw[3][1]));
    const float bmnz = fminf(fminf(bbw[0][2], bbw[1][2]), fminf(bbw[2][2], bbw[3][2]));
    const float bmxx = fmaxf(fmaxf(bbw[0][3], bbw[1][3]), fmaxf(bbw[2][3], bbw[3][3]));
    const float bmxy = fmaxf(fmaxf(bbw[0][4], bbw[1][4]), fmaxf(bbw[2][4], bbw[3][4]));
    const float bmxz = fmaxf(fmaxf(bbw[0][5], bbw[1][5]), fmaxf(bbw[2][5], bbw[3][5]));

    // pass A: home chunk
    unsigned long long key = 0xFFFFFFFFFFFFFFFFull;
    {
        int cellv = mcell(vx, vy, vz);
        int h = min(faceStart[cellv] >> 6, NCH - 1);
        int base = h * CHF + role;
#pragma unroll
        for (int i = 0; i < 8; ++i) {
            float4 b = faceAS[base + i * 8];
            int oi = origIdx[base + i * 8];
            float s = fmaf(-vx, b.x, b.w);
            s = fmaf(-vy, b.y, s);
            s = fmaf(-vz, b.z, s);
            unsigned u = enc_f32(s);
            unsigned long long k = ((unsigned long long)u << 32) | (unsigned)oi;
            key = (k < key) ? k : key;
        }
        unsigned long long o = __shfl_xor(key, 1); key = (o < key) ? o : key;
        o = __shfl_xor(key, 2); key = (o < key) ? o : key;
        o = __shfl_xor(key, 4); key = (o < key) ? o : key;
    }
    float d2best = 2.0f * dec_f32((unsigned)(key >> 32)) + vv;

    // block ub
    __shared__ float ubw[4];
    {
        float um = d2best;
        for (int d = 1; d < 64; d <<= 1) um = fmaxf(um, __shfl_xor(um, d));
        if ((t & 63) == 0) ubw[wv] = um;
    }
    __syncthreads();
    const float ub = fmaxf(fmaxf(ubw[0], ubw[1]), fmaxf(ubw[2], ubw[3])) + MARGIN;

    // survivor list (ordered ballot compaction; 256 threads = 256 chunks)
    __shared__ unsigned short surv[NCH];
    __shared__ int wcnt[4], wbase[4], nsurvS;
    bool flag;
    {
        float4 lo = bbLo[t], hi = bbHi[t];
        float gx = fmaxf(fmaxf(lo.x - bmxx, bmnx - hi.x), 0.0f);
        float gy = fmaxf(fmaxf(lo.y - bmxy, bmny - hi.y), 0.0f);
        float gz = fmaxf(fmaxf(lo.z - bmxz, bmnz - hi.z), 0.0f);
        flag = (gx * gx + gy * gy + gz * gz) <= ub;
    }
    unsigned long long bm = __ballot(flag);
    if ((t & 63) == 0) wcnt[wv] = __popcll(bm);
    __syncthreads();
    if (t == 0) {
        int s = 0;
        for (int w = 0; w < 4; ++w) { wbase[w] = s; s += wcnt[w]; }
        nsurvS = s;
    }
    __syncthreads();
    if (flag)
        surv[wbase[wv] + __popcll(bm & ((1ull << (t & 63)) - 1ull))] = (unsigned short)t;
    __syncthreads();
    const int nsurv = nsurvS;

    // main loop over survivors
    for (int si = 0; si < nsurv; ++si) {
        const int c = surv[si];
        float4 lo = bbLo[c], hi = bbHi[c];
        float gx = fmaxf(fmaxf(lo.x - vx, vx - hi.x), 0.0f);
        float gy = fmaxf(fmaxf(lo.y - vy, vy - hi.y), 0.0f);
        float gz = fmaxf(fmaxf(lo.z - vz, vz - hi.z), 0.0f);
        if (gx * gx + gy * gy + gz * gz <= d2best + MARGIN) {
            int base = c * CHF + role;
#pragma unroll
            for (int i = 0; i < 8; ++i) {
                float4 b = faceAS[base + i * 8];
                int oi = origIdx[base + i * 8];
                float s = fmaf(-vx, b.x, b.w);
                s = fmaf(-vy, b.y, s);
                s = fmaf(-vz, b.z, s);
                unsigned u = enc_f32(s);
                unsigned long long k = ((unsigned long long)u << 32) | (unsigned)oi;
                key = (k < key) ? k : key;
            }
        }
        unsigned long long o = __shfl_xor(key, 1); key = (o < key) ? o : key;
        o = __shfl_xor(key, 2); key = (o < key) ? o : key;
        o = __shfl_xor(key, 4); key = (o < key) ? o : key;
        d2best = 2.0f * dec_f32((unsigned)(key >> 32)) + vv;
    }

    if (role == 0) keys[n_orig] = key;
}

// ---------------------------------------------------------------------------
// K6: gather chosen face, current center + normal, cubic penalty, block sum
// ---------------------------------------------------------------------------
__global__ __launch_bounds__(256) void k_loss(
    const float* __restrict__ cloth_pred,
    const float* __restrict__ obs_pos,
    const int* __restrict__ faces,
    const unsigned long long* __restrict__ keys,
    float* __restrict__ lossPartial)
{
    const int t = threadIdx.x;
    const int n = blockIdx.x * blockDim.x + t;

    int idx = (int)(unsigned int)(keys[n] & 0xFFFFFFFFull);

    int i0 = faces[3 * idx + 0];
    int i1 = faces[3 * idx + 1];
    int i2 = faces[3 * idx + 2];
    float ux = obs_pos[3 * i0 + 0], uy = obs_pos[3 * i0 + 1], uz = obs_pos[3 * i0 + 2];
    float wx1 = obs_pos[3 * i1 + 0], wy1 = obs_pos[3 * i1 + 1], wz1 = obs_pos[3 * i1 + 2];
    float wx2 = obs_pos[3 * i2 + 0], wy2 = obs_pos[3 * i2 + 1], wz2 = obs_pos[3 * i2 + 2];

    float fpx = (ux + wx1 + wx2) * (1.0f / 3.0f);
    float fpy = (uy + wy1 + wy2) * (1.0f / 3.0f);
    float fpz = (uz + wz1 + wz2) * (1.0f / 3.0f);

    float e1x = wx1 - ux, e1y = wy1 - uy, e1z = wz1 - uz;
    float e2x = wx2 - ux, e2y = wy2 - uy, e2z = wz2 - uz;
    float nx = e1y * e2z - e1z * e2y;
    float ny = e1z * e2x - e1x * e2z;
    float nz = e1x * e2y - e1y * e2x;
    float nrm = sqrtf(nx * nx + ny * ny + nz * nz);
    float inv = 1.0f / fmaxf(nrm, 1e-12f);

    float px = cloth_pred[3 * n + 0];
    float py = cloth_pred[3 * n + 1];
    float pz = cloth_pred[3 * n + 2];
    float d = (px - fpx) * nx * inv + (py - fpy) * ny * inv + (pz - fpz) * nz * inv;
    float tt = fmaxf(1e-3f - d, 0.0f);
    float val = tt * tt * tt;

    __shared__ float red[256];
    red[t] = val;
    __syncthreads();
    for (int s = 128; s > 0; s >>= 1) {
        if (t < s) red[t] += red[t + s];
        __syncthreads();
    }
    if (t == 0) lossPartial[blockIdx.x] = red[0];
}

// ---------------------------------------------------------------------------
// K7: final 64-partial sum * weight(iteration) -> d_out[0]
// ---------------------------------------------------------------------------
__global__ __launch_bounds__(64) void k_final(
    const float* __restrict__ lossPartial,
    const int* __restrict__ iteration,
    float* __restrict__ out)
{
    int t = threadIdx.x;
    float v = lossPartial[t];
#pragma unroll
    for (int o = 32; o > 0; o >>= 1) v += __shfl_down(v, o);
    if (t == 0) {
        int it = iteration[0];
        float itf = fmaxf((float)(it - 50000), 0.0f);
        float prog = fminf(itf * (1.0f / 100000.0f), 1.0f);
        float w = 1.0f + (5000.0f - 1.0f) * prog;
        out[0] = v * w;
    }
}

extern "C" void kernel_launch(void* const* d_in, const int* in_sizes, int n_in,
                              void* d_out, int out_size, void* d_ws, size_t ws_size,
                              hipStream_t stream) {
    const float* obs_pos    = (const float*)d_in[0];
    const float* obs_prev   = (const float*)d_in[1];
    const int*   faces      = (const int*)d_in[2];
    const float* cloth_prev = (const float*)d_in[3];
    const float* cloth_pred = (const float*)d_in[4];
    const int*   iteration  = (const int*)d_in[5];
    float* out = (float*)d_out;

    char* ws = (char*)d_ws;
    float4* faceA     = (float4*)(ws + 0);         // 262144
    float4* faceAS    = (float4*)(ws + 262144);    // 262144
    int*    origIdx   = (int*)(ws + 524288);       // 65536
    int*    cellF     = (int*)(ws + 589824);       // 65536
    int*    cellV     = (int*)(ws + 655360);       // 65536
    float4* vertS     = (float4*)(ws + 720896);    // 262144
    int*    faceCnt   = (int*)(ws + 983040);       // 16384  \ zeroed
    int*    vertCnt   = (int*)(ws + 999424);       // 16384  /
    int*    faceStart = (int*)(ws + 1015808);      // 16384
    int*    cursorF   = (int*)(ws + 1032192);      // 16384
    int*    cursorV   = (int*)(ws + 1048576);      // 16384
    float4* bbLo      = (float4*)(ws + 1064960);   // 4096
    float4* bbHi      = (float4*)(ws + 1069056);   // 4096
    unsigned long long* keys = (unsigned long long*)(ws + 1073152);  // 131072
    float*  lossPartial = (float*)(ws + 1204224);  // 256

    hipMemsetAsync(ws + 983040, 0, 32768, stream);

    k_bin<<<N_OBS_FACES / 256, 256, 0, stream>>>(
        obs_prev, faces, cloth_prev, faceA, cellF, cellV, faceCnt, vertCnt);
    k_scan2<<<1, 1024, 0, stream>>>(faceCnt, vertCnt, faceStart, cursorF, cursorV);
    k_scatter<<<N_OBS_FACES / 256, 256, 0, stream>>>(
        faceA, cellF, cloth_prev, cellV, cursorF, cursorV, faceAS, origIdx, vertS);
    k_chunkbb<<<NCH, 64, 0, stream>>>(faceAS, bbLo, bbHi);
    k_nn_cull<<<N_CLOTH / K5_VB, 256, 0, stream>>>(
        vertS, faceAS, origIdx, faceStart, bbLo, bbHi, keys);
    k_loss<<<N_CLOTH / 256, 256, 0, stream>>>(cloth_pred, obs_pos, faces, keys, lossPartial);
    k_final<<<1, 64, 0, stream>>>(lossPartial, iteration, out);
}